// Round 6
// baseline (902.050 us; speedup 1.0000x reference)
//
#include <hip/hip_runtime.h>
#include <math.h>

#define H 1024
#define SEQ 2048
#define BATCH 8
#define N_ENT 1000
#define TOPK 5
#define LN_EPS 1e-5f
#define NB_SP 256

using bf16x8 = __attribute__((ext_vector_type(8))) __bf16;
using f32x4  = __attribute__((ext_vector_type(4))) float;
#define AS1 __attribute__((address_space(1)))
#define AS3 __attribute__((address_space(3)))

// ---------- helpers ----------

// fast erf-GELU: Abramowitz-Stegun 7.1.26, |erf err| <= 1.5e-7, hw rcp/exp2
__device__ __forceinline__ float gelu_fast(float x) {
    float z = fabsf(x) * 0.70710678118654752440f;
    float t = __builtin_amdgcn_rcpf(fmaf(0.3275911f, z, 1.0f));
    float p = fmaf(fmaf(fmaf(fmaf(1.061405429f, t, -1.453152027f), t, 1.421413741f),
                        t, -0.284496736f), t, 0.254829592f) * t;
    float e = __builtin_amdgcn_exp2f(-z * z * 1.44269504088896f);
    float erfz = fmaf(-p, e, 1.0f);
    float s = copysignf(erfz, x);
    return 0.5f * x * (1.0f + s);
}

__device__ __forceinline__ float sigmoidf_(float x) {
    return 1.0f / (1.0f + expf(-x));
}

__device__ __forceinline__ unsigned short f2bf(float f) {
    unsigned int u = __float_as_uint(f);
    unsigned int r = (u + 0x7fffu + ((u >> 16) & 1u)) >> 16;  // RNE
    return (unsigned short)r;
}

__device__ float block_sum(float v, float* red) {
    for (int off = 32; off > 0; off >>= 1) v += __shfl_down(v, off, 64);
    int wid = threadIdx.x >> 6;
    int lane = threadIdx.x & 63;
    int nw = blockDim.x >> 6;
    if (lane == 0) red[wid] = v;
    __syncthreads();
    if (threadIdx.x == 0) {
        float s = 0.f;
        for (int i = 0; i < nw; ++i) s += red[i];
        red[0] = s;
    }
    __syncthreads();
    float r = red[0];
    __syncthreads();
    return r;
}

// device-scope sense barrier for NB_SP co-resident blocks (R3-proven pattern).
__device__ __forceinline__ void gbar(unsigned* cnt, unsigned* gen) {
    __syncthreads();
    if (threadIdx.x == 0) {
        __threadfence();
        unsigned g = __hip_atomic_load(gen, __ATOMIC_RELAXED, __HIP_MEMORY_SCOPE_AGENT);
        unsigned a = __hip_atomic_fetch_add(cnt, 1u, __ATOMIC_ACQ_REL, __HIP_MEMORY_SCOPE_AGENT);
        if (a == NB_SP - 1) {
            __hip_atomic_store(cnt, 0u, __ATOMIC_RELAXED, __HIP_MEMORY_SCOPE_AGENT);
            __hip_atomic_fetch_add(gen, 1u, __ATOMIC_ACQ_REL, __HIP_MEMORY_SCOPE_AGENT);
        } else {
            while (__hip_atomic_load(gen, __ATOMIC_ACQUIRE, __HIP_MEMORY_SCOPE_AGENT) == g)
                __builtin_amdgcn_s_sleep(1);
        }
        __threadfence();
    }
    __syncthreads();
}

// per-row LN over H=1024 from k-split partials [nks][8][1024]; 256 threads, 4 cols/thread
__device__ void reduce_ln_sp(const float* part, const float* bias, const float* g,
                             const float* be, float* out, int nks, int b, float* red) {
    int t = threadIdx.x;
    float4 s = *(const float4*)(bias + t * 4);
    for (int ks = 0; ks < nks; ++ks) {
        float4 p = *(const float4*)(part + (((size_t)(ks * 8 + b)) << 10) + t * 4);
        s.x += p.x; s.y += p.y; s.z += p.z; s.w += p.w;
    }
    float mu = block_sum(s.x + s.y + s.z + s.w, red) * (1.0f / H);
    float4 d = {s.x - mu, s.y - mu, s.z - mu, s.w - mu};
    float var = block_sum(d.x * d.x + d.y * d.y + d.z * d.z + d.w * d.w, red) * (1.0f / H);
    float inv = rsqrtf(var + LN_EPS);
    float4 gg = *(const float4*)(g + t * 4);
    float4 bb = *(const float4*)(be + t * 4);
    float4 o = {d.x * inv * gg.x + bb.x, d.y * inv * gg.y + bb.y,
                d.z * inv * gg.z + bb.z, d.w * inv * gg.w + bb.w};
    *(float4*)(out + ((size_t)b << 10) + t * 4) = o;
}

// ---------- conversion kernels ----------

__global__ void f2bf_kernel(const float* __restrict__ in, unsigned short* __restrict__ out, int n) {
    int i = (blockIdx.x * blockDim.x + threadIdx.x) * 4;
    if (i >= n) return;
    float4 v = *(const float4*)(in + i);
    ushort4 o;
    o.x = f2bf(v.x); o.y = f2bf(v.y); o.z = f2bf(v.z); o.w = f2bf(v.w);
    *(ushort4*)(out + i) = o;
}

// both weight transposes in one launch. bid<2048: ee_w1 (1024x2048); else ee_w2 (2048x1024)
__global__ void transpose_both_kernel(const float* __restrict__ w1, unsigned short* __restrict__ o1,
                                      const float* __restrict__ w2, unsigned short* __restrict__ o2) {
    __shared__ float tile[32][33];
    int bid = blockIdx.x;
    const float* in; unsigned short* out; int R, C, bx, by;
    if (bid < 2048) { in = w1; out = o1; R = 1024; C = 2048; bx = bid & 63; by = bid >> 6; }
    else { bid -= 2048; in = w2; out = o2; R = 2048; C = 1024; bx = bid & 31; by = bid >> 5; }
    int c0 = bx * 32, r0 = by * 32;
    int tx = threadIdx.x & 31, ty = threadIdx.x >> 5;
#pragma unroll
    for (int i = 0; i < 32; i += 8)
        tile[ty + i][tx] = in[(size_t)(r0 + ty + i) * C + c0 + tx];
    __syncthreads();
#pragma unroll
    for (int i = 0; i < 32; i += 8)
        out[(size_t)(c0 + ty + i) * R + r0 + tx] = f2bf(tile[tx][ty + i]);
}

// ---------- the ENTIRE small path: one persistent kernel, 256 blocks x 256 threads ----------
// Independent of stream1 (reads only hs + weights); 12 device barriers.
// LDS exactly 32 KB so a gemm block (128 KB) can co-reside on the same CU.

__global__ __launch_bounds__(256) void small_path_kernel(
    const float* __restrict__ hs, const float* __restrict__ ent,
    const float* re_w1, const float* re_b1, const float* re_w2, const float* re_b2,
    const float* re_g, const float* re_be,
    const float* rn_w1, const float* rn_b1, const float* rn_w2, const float* rn_b2,
    const float* rn_g, const float* rn_be,
    const float* vn_w1, const float* vn_b1, const float* vn_w2, const float* vn_b2,
    float* sp_pool, float* sp1, float* sp2, float* pooled, float* xin, int* idx_i,
    float* rel, float* sims, float* tidx, float* retr, float* ro, float* vs,
    unsigned* bar) {
    __shared__ __align__(16) float um[8192];   // 32768 B exactly
    unsigned* cnt = bar;
    unsigned* gen = bar + 1;
    const int bid = blockIdx.x;
    const int t = threadIdx.x;

    // ---- S0: pooling partials (own hs read; 256 blocks x 64 rows) ----
    {
        int b = bid >> 5, sc = bid & 31;
        const float* p = hs + ((size_t)b * SEQ + sc * 64) * H + t * 4;
        float4 a = {0.f, 0.f, 0.f, 0.f};
        for (int s = 0; s < 64; ++s) {
            float4 v = *(const float4*)(p + (size_t)s * H);
            a.x += v.x; a.y += v.y; a.z += v.z; a.w += v.w;
        }
        *(float4*)(sp_pool + (((size_t)(b * 32 + sc)) << 10) + t * 4) = a;
    }
    gbar(cnt, gen);

    // ---- S1: pooled[8][1024] ----
    if (bid < 32) {
        int b = bid >> 2, col = (bid & 3) * 256 + t;
        float s = 0.f;
        for (int sc = 0; sc < 32; ++sc) s += sp_pool[(((size_t)(b * 32 + sc)) << 10) + col];
        pooled[((size_t)b << 10) + col] = s * (1.0f / SEQ);
    }
    gbar(cnt, gen);

    // ---- S2: re layer1 partial (jb 4 x ks 64, KR=16) ----
    {
        float* xs = um;
        int jb = bid & 3, ks = bid >> 2, k0 = ks * 16;
        if (t < 128) xs[t] = pooled[(((size_t)(t >> 4)) << 10) + k0 + (t & 15)];
        __syncthreads();
        int j = jb * 256 + t;
        float acc[8] = {};
        for (int k = 0; k < 16; ++k) {
            float w = re_w1[(size_t)(k0 + k) * H + j];
#pragma unroll
            for (int b = 0; b < 8; ++b) acc[b] = fmaf(xs[b * 16 + k], w, acc[b]);
        }
#pragma unroll
        for (int b = 0; b < 8; ++b) sp1[(((size_t)(ks * 8 + b)) << 10) + j] = acc[b];
    }
    gbar(cnt, gen);

    // ---- S3: re layer2 fused partial (reduce 64 + gelu on the fly; KR=16) ----
    {
        float* xs = um;
        float* xr = um + 256;
        int jb = bid & 3, ks = bid >> 2, k0 = ks * 16;
        {
            int e = t >> 1, h = t & 1;
            int b = e >> 4, c = k0 + (e & 15);
            float s = h ? 0.f : re_b1[c];
            for (int q = h * 32; q < h * 32 + 32; ++q) s += sp1[(((size_t)(q * 8 + b)) << 10) + c];
            xr[t] = s;
        }
        __syncthreads();
        if (t < 128) xs[t] = gelu_fast(xr[2 * t] + xr[2 * t + 1]);
        __syncthreads();
        int j = jb * 256 + t;
        float acc[8] = {};
        for (int k = 0; k < 16; ++k) {
            float w = re_w2[(size_t)(k0 + k) * H + j];
#pragma unroll
            for (int b = 0; b < 8; ++b) acc[b] = fmaf(xs[b * 16 + k], w, acc[b]);
        }
#pragma unroll
        for (int b = 0; b < 8; ++b) sp2[(((size_t)(ks * 8 + b)) << 10) + j] = acc[b];
    }
    gbar(cnt, gen);

    // ---- S4: re LN -> rel ----
    if (bid < 8) reduce_ln_sp(sp2, re_b2, re_g, re_be, rel, 64, bid, um);
    gbar(cnt, gen);

    // ---- S5: sims (250 blocks x 4 entities) ----
    if (bid < 250) {
        float* rl = um;
        for (int i = t; i < 8192; i += 256) rl[i] = rel[i];
        __syncthreads();
        int e = bid * 4 + (t >> 6), lane = t & 63;
        const float* ep = ent + (size_t)e * H;
        float ev[16];
#pragma unroll
        for (int i = 0; i < 16; ++i) ev[i] = ep[lane + i * 64];
#pragma unroll
        for (int b = 0; b < 8; ++b) {
            float a = 0.f;
#pragma unroll
            for (int i = 0; i < 16; ++i) a = fmaf(ev[i], rl[b * 1024 + lane + i * 64], a);
            for (int off = 32; off > 0; off >>= 1) a += __shfl_down(a, off, 64);
            if (lane == 0) sims[b * N_ENT + e] = a;
        }
    }
    gbar(cnt, gen);

    // ---- S6: top-k (8 blocks) ----
    if (bid < 8) {
        float* tv = um;
        float* trv = um + 1024;
        int* tri = (int*)(um + 1028);
        int b = bid;
        for (int i = t; i < 1024; i += 256) tv[i] = (i < N_ENT) ? sims[b * N_ENT + i] : -INFINITY;
        __syncthreads();
        for (int k = 0; k < TOPK; ++k) {
            float best = -INFINITY;
            int bi = 0x7fffffff;
            for (int i = t; i < 1024; i += 256) {
                float x = tv[i];
                if (x > best || (x == best && i < bi)) { best = x; bi = i; }
            }
            for (int off = 32; off > 0; off >>= 1) {
                float ov = __shfl_down(best, off, 64);
                int oi = __shfl_down(bi, off, 64);
                if (ov > best || (ov == best && oi < bi)) { best = ov; bi = oi; }
            }
            if ((t & 63) == 0) { trv[t >> 6] = best; tri[t >> 6] = bi; }
            __syncthreads();
            if (t == 0) {
                for (int w2 = 1; w2 < 4; ++w2)
                    if (trv[w2] > trv[0] || (trv[w2] == trv[0] && tri[w2] < tri[0])) { trv[0] = trv[w2]; tri[0] = tri[w2]; }
                int sel = tri[0];
                tidx[b * TOPK + k] = (float)sel;
                idx_i[b * TOPK + k] = sel;
                tv[sel] = -INFINITY;
            }
            __syncthreads();
        }
    }
    gbar(cnt, gen);

    // ---- S7: gather retrieved + build xin ----
    if (bid < 8) {
        int b = bid;
#pragma unroll
        for (int u = 0; u < 4; ++u) {
            int h = u * 256 + t;
            float acc = 0.f;
            for (int k = 0; k < TOPK; ++k) {
                float v = ent[(size_t)idx_i[b * TOPK + k] * H + h];
                retr[((size_t)(b * TOPK + k)) * H + h] = v;
                acc += v;
            }
            xin[(size_t)b * 3072 + h] = acc * (1.0f / TOPK);
            xin[(size_t)b * 3072 + 1024 + h] = rel[b * 1024 + h];
            xin[(size_t)b * 3072 + 2048 + h] = pooled[b * 1024 + h];
        }
    }
    gbar(cnt, gen);

    // ---- S8: rn layer1 partial (jb 8 x ks 32, KR=96) ----
    {
        float* xs = um;
        int jb = bid & 7, ks = bid >> 3, k0 = ks * 96;
        for (int i = t; i < 768; i += 256) {
            int b = i / 96, k = i - b * 96;
            xs[i] = xin[(size_t)b * 3072 + k0 + k];
        }
        __syncthreads();
        int j = jb * 256 + t;
        float acc[8] = {};
        for (int k = 0; k < 96; ++k) {
            float w = rn_w1[(size_t)(k0 + k) * 2048 + j];
#pragma unroll
            for (int b = 0; b < 8; ++b) acc[b] = fmaf(xs[b * 96 + k], w, acc[b]);
        }
#pragma unroll
        for (int b = 0; b < 8; ++b) sp1[((size_t)(ks * 8 + b)) * 2048 + j] = acc[b];
    }
    gbar(cnt, gen);

    // ---- S9: rn layer2 fused partial (reduce 32 + gelu; jb 4 x ks 64, KR=32) ----
    {
        float* xs = um;
        int jb = bid & 3, ks = bid >> 2, k0 = ks * 32;
        {
            int b = t >> 5, c = k0 + (t & 31);
            float s = rn_b1[c];
            for (int q = 0; q < 32; ++q) s += sp1[((size_t)(q * 8 + b)) * 2048 + c];
            xs[t] = gelu_fast(s);
        }
        __syncthreads();
        int j = jb * 256 + t;
        float acc[8] = {};
        for (int k = 0; k < 32; ++k) {
            float w = rn_w2[(size_t)(k0 + k) * 1024 + j];
#pragma unroll
            for (int b = 0; b < 8; ++b) acc[b] = fmaf(xs[b * 32 + k], w, acc[b]);
        }
#pragma unroll
        for (int b = 0; b < 8; ++b) sp2[(((size_t)(ks * 8 + b)) << 10) + j] = acc[b];
    }
    gbar(cnt, gen);

    // ---- S10: rn LN -> ro ----
    if (bid < 8) reduce_ln_sp(sp2, rn_b2, rn_g, rn_be, ro, 64, bid, um);
    gbar(cnt, gen);

    // ---- S11: vn layer1 partial (jb 2 x ks 32, KR=32; 64 blocks) ----
    if (bid < 64) {
        float* xs = um;
        int jb = bid & 1, ks = bid >> 1, k0 = ks * 32;
        {
            int b = t >> 5;
            xs[t] = ro[((size_t)b << 10) + k0 + (t & 31)];
        }
        __syncthreads();
        int j = jb * 256 + t;
        float acc[8] = {};
        for (int k = 0; k < 32; ++k) {
            float w = vn_w1[(size_t)(k0 + k) * 512 + j];
#pragma unroll
            for (int b = 0; b < 8; ++b) acc[b] = fmaf(xs[b * 32 + k], w, acc[b]);
        }
#pragma unroll
        for (int b = 0; b < 8; ++b) sp1[((size_t)(ks * 8 + b)) * 512 + j] = acc[b];
    }
    gbar(cnt, gen);

    // ---- S12: vn reduce + gelu + dot + sigmoid ----
    if (bid < 8) {
        int b = bid;
        float c = 0.f;
#pragma unroll
        for (int u = 0; u < 2; ++u) {
            int e = u * 256 + t;
            float s = vn_b1[e];
            for (int q = 0; q < 32; ++q) s += sp1[((size_t)(q * 8 + b)) * 512 + e];
            c += gelu_fast(s) * vn_w2[e];
        }
        float tot = block_sum(c, um);
        if (t == 0) vs[b] = sigmoidf_(tot + vn_b2[0]);
    }
}

// ---------- bf16 MFMA GEMM: 256x256 tile, BK=64, 8 waves, 4-phase schedule ----------
// (unchanged from R5: counted-vmcnt pipeline, XOR-swizzled LDS reads, setprio,
// bijective XCD swizzle, direct-store epilogue)
template <int GELU_BF16_OUT>
__global__ __launch_bounds__(512, 2) void gemm256_8ph(const unsigned short* __restrict__ A,
                                                      const unsigned short* __restrict__ Bt,
                                                      const float* __restrict__ bias,
                                                      void* __restrict__ Cout,
                                                      int M, int N, int K) {
    __shared__ __align__(16) unsigned short As[4][128 * 64];
    __shared__ __align__(16) unsigned short Bs[4][128 * 64];
    const int tid = threadIdx.x;
    const int lane = tid & 63;
    const int w = tid >> 6;
    const int wm2 = w >> 2;   // 0..1
    const int wn4 = w & 3;    // 0..3

    const int Np = N >> 8;
    const int nwg = gridDim.x;
    int bid = blockIdx.x;
    int s = bid;
    if ((nwg & 7) == 0) s = (bid & 7) * (nwg >> 3) + (bid >> 3);  // XCD-chunked, bijective
    const int m0 = (s / Np) << 8;
    const int n0 = (s % Np) << 8;

    const int nT = K >> 6;

    const int l7 = lane & 7;
    const int lrow0 = w * 16 + (lane >> 3);
    const int lrow1 = lrow0 + 8;
    const int kel0 = ((l7 ^ (lrow0 & 7)) << 3);   // pre-swizzled k element offset
    const int kel1 = ((l7 ^ (lrow1 & 7)) << 3);
    const unsigned short* pa0 = A + (size_t)(m0 + lrow0) * K + kel0;
    const unsigned short* pa1 = A + (size_t)(m0 + lrow1) * K + kel1;
    const unsigned short* pb0 = Bt + (size_t)(n0 + lrow0) * K + kel0;
    const unsigned short* pb1 = Bt + (size_t)(n0 + lrow1) * K + kel1;
    const size_t halfstep = (size_t)128 * K;
    const int dst0 = (w * 16) * 64;
    const int dst1 = dst0 + 8 * 64;

    auto stageA = [&](int t, int half) {
        if (t >= nT) return;
        int slot = (2 * t + half) & 3;
        int koff = t << 6;
        __builtin_amdgcn_global_load_lds((AS1 void*)(pa0 + half * halfstep + koff),
                                         (AS3 void*)(&As[slot][dst0]), 16, 0, 0);
        __builtin_amdgcn_global_load_lds((AS1 void*)(pa1 + half * halfstep + koff),
                                         (AS3 void*)(&As[slot][dst1]), 16, 0, 0);
    };
    auto stageB = [&](int t, int half) {
        if (t >= nT) return;
        int slot = (2 * t + half) & 3;
        int koff = t << 6;
        __builtin_amdgcn_global_load_lds((AS1 void*)(pb0 + half * halfstep + koff),
                                         (AS3 void*)(&Bs[slot][dst0]), 16, 0, 0);
        __builtin_amdgcn_global_load_lds((AS1 void*)(pb1 + half * halfstep + koff),
                                         (AS3 void*)(&Bs[slot][dst1]), 16, 0, 0);
    };

    const int arow = lane & 15;
    const int xk0 = (((lane >> 4) << 4)) ^ (l7 << 4);
    const int xk1 = (64 + ((lane >> 4) << 4)) ^ (l7 << 4);
    auto ldf = [&](const unsigned short* slotbase, int rowbase, int xk) -> bf16x8 {
        return *(const bf16x8*)((const char*)slotbase + (rowbase + arow) * 128 + xk);
    };

    f32x4 acc[8][4] = {};

    stageA(0, 0); stageB(0, 0); stageA(0, 1); stageB(0, 1);
    stageA(1, 0); stageB(1, 0); stageB(1, 1);
    asm volatile("s_waitcnt vmcnt(10)" ::: "memory");
    __builtin_amdgcn_s_barrier();

    bf16x8 af0[4][2], af1[4][2], bf0[2][2], bf1[2][2];

    for (int T = 0; T < nT; ++T) {
        const unsigned short* Aslot0 = As[(2 * T) & 3];
        const unsigned short* Aslot1 = As[(2 * T + 1) & 3];
        const unsigned short* Bslot0 = Bs[(2 * T) & 3];
        const unsigned short* Bslot1 = Bs[(2 * T + 1) & 3];

        // ---- phase 1: (ih0, jh0) ----
#pragma unroll
        for (int ii = 0; ii < 4; ++ii) {
            af0[ii][0] = ldf(Aslot0, ii * 32 + wm2 * 16, xk0);
            af0[ii][1] = ldf(Aslot0, ii * 32 + wm2 * 16, xk1);
        }
#pragma unroll
        for (int jj = 0; jj < 2; ++jj) {
            bf0[jj][0] = ldf(Bslot0, jj * 64 + wn4 * 16, xk0);
            bf0[jj][1] = ldf(Bslot0, jj * 64 + wn4 * 16, xk1);
        }
        stageA(T + 1, 1);
        __builtin_amdgcn_s_barrier();
        __builtin_amdgcn_s_setprio(1);
#pragma unroll
        for (int ii = 0; ii < 4; ++ii)
#pragma unroll
            for (int jj = 0; jj < 2; ++jj) {
                acc[ii][jj] = __builtin_amdgcn_mfma_f32_16x16x32_bf16(af0[ii][0], bf0[jj][0], acc[ii][jj], 0, 0, 0);
                acc[ii][jj] = __builtin_amdgcn_mfma_f32_16x16x32_bf16(af0[ii][1], bf0[jj][1], acc[ii][jj], 0, 0, 0);
            }
        __builtin_amdgcn_s_setprio(0);
        if (T == 0) asm volatile("s_waitcnt vmcnt(8)" ::: "memory");
        else        asm volatile("s_waitcnt vmcnt(10)" ::: "memory");
        __builtin_amdgcn_s_barrier();

        // ---- phase 2: (ih0, jh1) ----
#pragma unroll
        for (int jj = 0; jj < 2; ++jj) {
            bf1[jj][0] = ldf(Bslot1, jj * 64 + wn4 * 16, xk0);
            bf1[jj][1] = ldf(Bslot1, jj * 64 + wn4 * 16, xk1);
        }
        stageA(T + 2, 0);
        __builtin_amdgcn_s_barrier();
        __builtin_amdgcn_s_setprio(1);
#pragma unroll
        for (int ii = 0; ii < 4; ++ii)
#pragma unroll
            for (int jj = 0; jj < 2; ++jj) {
                acc[ii][2 + jj] = __builtin_amdgcn_mfma_f32_16x16x32_bf16(af0[ii][0], bf1[jj][0], acc[ii][2 + jj], 0, 0, 0);
                acc[ii][2 + jj] = __builtin_amdgcn_mfma_f32_16x16x32_bf16(af0[ii][1], bf1[jj][1], acc[ii][2 + jj], 0, 0, 0);
            }
        __builtin_amdgcn_s_setprio(0);
        if (T + 2 >= nT) asm volatile("s_waitcnt vmcnt(8)" ::: "memory");
        else             asm volatile("s_waitcnt vmcnt(10)" ::: "memory");
        __builtin_amdgcn_s_barrier();

        // ---- phase 3: (ih1, jh0) ----
#pragma unroll
        for (int ii = 0; ii < 4; ++ii) {
            af1[ii][0] = ldf(Aslot1, ii * 32 + wm2 * 16, xk0);
            af1[ii][1] = ldf(Aslot1, ii * 32 + wm2 * 16, xk1);
        }
        stageB(T + 2, 0);
        __builtin_amdgcn_s_barrier();
        __builtin_amdgcn_s_setprio(1);
#pragma unroll
        for (int ii = 0; ii < 4; ++ii)
#pragma unroll
            for (int jj = 0; jj < 2; ++jj) {
                acc[4 + ii][jj] = __builtin_amdgcn_mfma_f32_16x16x32_bf16(af1[ii][0], bf0[jj][0], acc[4 + ii][jj], 0, 0, 0);
                acc[4 + ii][jj] = __builtin_amdgcn_mfma_f32_16x16x32_bf16(af1[ii][1], bf0[jj][1], acc[4 + ii][jj], 0, 0, 0);
            }
        __builtin_amdgcn_s_setprio(0);
        __builtin_amdgcn_s_barrier();

        // ---- phase 4: (ih1, jh1) ----
        stageB(T + 2, 1);
        __builtin_amdgcn_s_barrier();
        __builtin_amdgcn_s_setprio(1);
#pragma unroll
        for (int ii = 0; ii < 4; ++ii)
#pragma unroll
            for (int jj = 0; jj < 2; ++jj) {
                acc[4 + ii][2 + jj] = __builtin_amdgcn_mfma_f32_16x16x32_bf16(af1[ii][0], bf1[jj][0], acc[4 + ii][2 + jj], 0, 0, 0);
                acc[4 + ii][2 + jj] = __builtin_amdgcn_mfma_f32_16x16x32_bf16(af1[ii][1], bf1[jj][1], acc[4 + ii][2 + jj], 0, 0, 0);
            }
        __builtin_amdgcn_s_setprio(0);
        if (T + 2 < nT) asm volatile("s_waitcnt vmcnt(10)" ::: "memory");
        else            asm volatile("s_waitcnt vmcnt(0)" ::: "memory");
        __builtin_amdgcn_s_barrier();
    }

    // C/D layout: col=lane&15, row=(lane>>4)*4+r  [m89]
    const int cn = lane & 15;
    const int rbase = (lane >> 4) * 4;
#pragma unroll
    for (int i = 0; i < 8; ++i) {
        int mbase = m0 + (i >> 2) * 128 + (i & 3) * 32 + wm2 * 16 + rbase;
#pragma unroll
        for (int j = 0; j < 4; ++j) {
            int n = n0 + (j >> 1) * 128 + (j & 1) * 64 + wn4 * 16 + cn;
            float bv = bias[n];
#pragma unroll
            for (int r = 0; r < 4; ++r) {
                float c = acc[i][j][r] + bv;
                if (GELU_BF16_OUT) {
                    c = gelu_fast(c);
                    ((unsigned short*)Cout)[(size_t)(mbase + r) * N + n] = f2bf(c);
                } else {
                    ((float*)Cout)[(size_t)(mbase + r) * N + n] = c;
                }
            }
        }
    }
}

// per-row LayerNorm in place, float4. grid rows, block 256
__global__ void ln_rows_kernel(float* __restrict__ x, const float* __restrict__ g,
                               const float* __restrict__ beta) {
    __shared__ float red[32];
    float* p = x + (size_t)blockIdx.x * H;
    int t = threadIdx.x;
    float4 v = *(const float4*)(p + t * 4);
    float s = v.x + v.y + v.z + v.w;
    float mu = block_sum(s, red) * (1.0f / H);
    float4 d = { v.x - mu, v.y - mu, v.z - mu, v.w - mu };
    float d2 = d.x * d.x + d.y * d.y + d.z * d.z + d.w * d.w;
    float var = block_sum(d2, red) * (1.0f / H);
    float inv = rsqrtf(var + LN_EPS);
    float4 gg = *(const float4*)(g + t * 4);
    float4 bb = *(const float4*)(beta + t * 4);
    float4 o = { d.x * inv * gg.x + bb.x, d.y * inv * gg.y + bb.y,
                 d.z * inv * gg.z + bb.z, d.w * inv * gg.w + bb.w };
    *(float4*)(p + t * 4) = o;
}

// ---------- launch ----------

// fork-join resources (created once; R2 verified this pattern is capture-legal here)
static hipStream_t g_s2 = nullptr;
static hipEvent_t g_evF = nullptr, g_evJ = nullptr;
static int g_aux_tried = 0;

extern "C" void kernel_launch(void* const* d_in, const int* in_sizes, int n_in,
                              void* d_out, int out_size, void* d_ws, size_t ws_size,
                              hipStream_t stream) {
    const float* hs     = (const float*)d_in[0];
    const float* ent    = (const float*)d_in[1];
    const float* ee_w1  = (const float*)d_in[2];
    const float* ee_b1  = (const float*)d_in[3];
    const float* ee_w2  = (const float*)d_in[4];
    const float* ee_b2  = (const float*)d_in[5];
    const float* ee_g   = (const float*)d_in[6];
    const float* ee_be  = (const float*)d_in[7];
    const float* re_w1  = (const float*)d_in[8];
    const float* re_b1  = (const float*)d_in[9];
    const float* re_w2  = (const float*)d_in[10];
    const float* re_b2  = (const float*)d_in[11];
    const float* re_g   = (const float*)d_in[12];
    const float* re_be  = (const float*)d_in[13];
    const float* rn_w1  = (const float*)d_in[14];
    const float* rn_b1  = (const float*)d_in[15];
    const float* rn_w2  = (const float*)d_in[16];
    const float* rn_b2  = (const float*)d_in[17];
    const float* rn_g   = (const float*)d_in[18];
    const float* rn_be  = (const float*)d_in[19];
    const float* vn_w1  = (const float*)d_in[20];
    const float* vn_b1  = (const float*)d_in[21];
    const float* vn_w2  = (const float*)d_in[22];
    const float* vn_b2  = (const float*)d_in[23];

    float* out = (float*)d_out;
    float* ef   = out;
    float* rel  = ef + (size_t)BATCH * SEQ * H;
    float* retr = rel + BATCH * H;
    float* sims = retr + BATCH * TOPK * H;
    float* tidx = sims + BATCH * N_ENT;
    float* ro   = tidx + BATCH * TOPK;
    float* vs   = ro + BATCH * H;

    float* ws = (float*)d_ws;
    size_t o = 0;
    float* pooled  = ws + o; o += 8192;
    int*   idx_i   = (int*)(ws + o); o += 64;
    unsigned* bar  = (unsigned*)(ws + o); o += 16;
    float* xin     = ws + o; o += 8 * 3 * H;
    float* sp_pool = ws + o; o += 256 * 1024;     // 1 MB pooling partials
    float* sp1     = ws + o; o += 524288;         // 2 MB k-split partials
    float* sp2     = ws + o; o += 524288;         // 2 MB k-split partials
    unsigned short* w1t = (unsigned short*)(ws + o); o += (2048 * 1024) / 2;
    unsigned short* w2t = (unsigned short*)(ws + o); o += (2048 * 1024) / 2;
    unsigned short* hsb = (unsigned short*)(ws + o);

    long long avail = (long long)(ws_size / 4) - (long long)o;
    int chunk = (int)(avail / 1536);  // per row: 512 (hsb) + 1024 (mid) floats
    chunk &= ~255;                    // 256-row tiles
    int total = BATCH * SEQ;
    if (chunk > total) chunk = total;
    if (chunk < 256) chunk = 256;
    bool full = (chunk >= total);
    unsigned short* midb = hsb + (size_t)chunk * H;

    // lazy one-time creation of second stream + fork/join events
    if (!g_aux_tried) {
        g_aux_tried = 1;
        if (hipStreamCreateWithFlags(&g_s2, hipStreamNonBlocking) != hipSuccess) g_s2 = nullptr;
        if (g_s2) {
            if (hipEventCreateWithFlags(&g_evF, hipEventDisableTiming) != hipSuccess) g_evF = nullptr;
            if (hipEventCreateWithFlags(&g_evJ, hipEventDisableTiming) != hipSuccess) g_evJ = nullptr;
        }
    }
    const bool fork = (g_s2 && g_evF && g_evJ);
    hipStream_t sm = fork ? g_s2 : stream;

    // ---- fork FIRST: the small path is fully independent of the gemm path ----
    if (fork) {
        hipEventRecord(g_evF, stream);
        hipStreamWaitEvent(g_s2, g_evF, 0);
    }
    hipMemsetAsync(bar, 0, 2 * sizeof(unsigned), sm);
    small_path_kernel<<<NB_SP, 256, 0, sm>>>(
        hs, ent,
        re_w1, re_b1, re_w2, re_b2, re_g, re_be,
        rn_w1, rn_b1, rn_w2, rn_b2, rn_g, rn_be,
        vn_w1, vn_b1, vn_w2, vn_b2,
        sp_pool, sp1, sp2, pooled, xin, idx_i,
        rel, sims, tidx, retr, ro, vs, bar);
    if (fork) hipEventRecord(g_evJ, g_s2);

    // ---- main path: hs->bf16, weight prep, entity encoder, LN ----
    if (full) {
        f2bf_kernel<<<(total * H / 4) / 256, 256, 0, stream>>>(hs, hsb, total * H);
    }
    transpose_both_kernel<<<4096, 256, 0, stream>>>(ee_w1, w1t, ee_w2, w2t);

    for (int r0 = 0; r0 < total; r0 += chunk) {
        int m = total - r0;
        if (m > chunk) m = chunk;
        if (!full) {
            int nconv = m * H;
            f2bf_kernel<<<(nconv / 4 + 255) / 256, 256, 0, stream>>>(hs + (size_t)r0 * H, hsb, nconv);
        }
        unsigned short* a1 = full ? (hsb + (size_t)r0 * H) : hsb;
        gemm256_8ph<1><<<(m / 256) * (2048 / 256), 512, 0, stream>>>(a1, w1t, ee_b1, midb,
                                                                     m, 2048, 1024);
        gemm256_8ph<0><<<(m / 256) * (1024 / 256), 512, 0, stream>>>(midb, w2t, ee_b2,
                                                                     ef + (size_t)r0 * H,
                                                                     m, 1024, 2048);
    }
    ln_rows_kernel<<<total, 256, 0, stream>>>(ef, ee_g, ee_be);

    if (fork) hipStreamWaitEvent(stream, g_evJ, 0);
}